// Round 11
// baseline (193.769 us; speedup 1.0000x reference)
//
#include <hip/hip_runtime.h>
#include <cstdint>

typedef __bf16 bf16_t;
typedef __bf16 bf16x4 __attribute__((ext_vector_type(4)));
typedef __bf16 bf16x8 __attribute__((ext_vector_type(8)));
typedef float floatx4 __attribute__((ext_vector_type(4)));

#define EMBED 1024
#define NHEAD 16
#define HDIM  64
#define SEQ   2048
#define BATCH 2
#define MTOT  (BATCH*SEQ)   /* 4096 */
// Q is pre-scaled by 1/sqrt(64) * log2(e) so softmax can use exp2
#define QSCALE 0.18033688011112042f

// async global->LDS, 16B per lane; LDS dest = wave-uniform base + lane*16
__device__ __forceinline__ void gload16(const bf16_t* g, bf16_t* l) {
    __builtin_amdgcn_global_load_lds(
        (const __attribute__((address_space(1))) void*)g,
        (__attribute__((address_space(3))) void*)l, 16, 0, 0);
}

// ---------------------------------------------------------------------------
// z<4 : transpose fp32 weight z into bf16 [n][k] (W^T)
// z>=4: straight convert slab z-4 of x fp32 -> bf16
// ---------------------------------------------------------------------------
__global__ __launch_bounds__(256) void transpose4(
    const float* __restrict__ w0, const float* __restrict__ w1,
    const float* __restrict__ w2, const float* __restrict__ w3,
    const float* __restrict__ xin,
    bf16_t* __restrict__ out, bf16_t* __restrict__ xout)
{
    int z = blockIdx.z;
    int tx = threadIdx.x, ty = threadIdx.y;   // block (32,8)
    if (z >= 4) {
        const float* src = xin  + (size_t)(z - 4) * 1048576u;
        bf16_t*      dst = xout + (size_t)(z - 4) * 1048576u;
        int col = blockIdx.x * 32 + tx, rowb = blockIdx.y * 32;
#pragma unroll
        for (int j = 0; j < 4; j++) {
            int rr = rowb + ty + 8 * j;
            dst[(size_t)rr * 1024 + col] = (bf16_t)src[(size_t)rr * 1024 + col];
        }
        return;
    }
    __shared__ float t[32][33];
    const float* src = (z == 0) ? w0 : (z == 1) ? w1 : (z == 2) ? w2 : w3;
    bf16_t* dst = out + (size_t)z * 1048576u;
    int bx = blockIdx.x * 32, by = blockIdx.y * 32;
#pragma unroll
    for (int j = 0; j < 4; j++)
        t[ty + 8 * j][tx] = src[(size_t)(by + ty + 8 * j) * EMBED + bx + tx];
    __syncthreads();
#pragma unroll
    for (int j = 0; j < 4; j++)
        dst[(size_t)(bx + ty + 8 * j) * EMBED + by + tx] = (bf16_t)t[tx][ty + 8 * j];
}

// ---------------------------------------------------------------------------
// MFMA GEMM v2 (unchanged from R10): global_load_lds DMA + LDS double-buffer
// + one barrier per K-iter; XOR chunk swizzle via DMA source address; 1-D
// grid with XCD swizzle (id%8 = m-group).
// MODE 0: fp32 out row-major.
// MODE 1: fused QKV. Q/K tiles (n0<2048) scatter to bf16 [b,h,s,d] (Q scaled
//         by QSCALE). V tiles (n0>=2048) transpose through LDS and write
//         Vt [b,h,d,s'] with the PV-operand key permutation folded in.
// ---------------------------------------------------------------------------
template<int BM, int MODE>
__global__ __launch_bounds__(256) void gemm_t(
    const bf16_t* __restrict__ A,  const bf16_t* __restrict__ Bt,
    const float* __restrict__ bias0, const float* __restrict__ bias1,
    const float* __restrict__ bias2,
    void* __restrict__ outraw, bf16_t* __restrict__ vtout,
    int M, int N, int K)
{
    constexpr int MS = BM / 32;          // m-subtiles per wave
    constexpr int BUFSZ = (BM + 128) * 64;
    __shared__ __align__(16) bf16_t smem[2 * BUFSZ];

    int tid  = threadIdx.x;
    int id   = blockIdx.x;
    int c8   = id & 7, rr_ = id >> 3;
    int nblk = N >> 7;
    int n0   = (rr_ % nblk) * 128;
    int m0   = ((rr_ / nblk) * 8 + c8) * BM;
    int wv   = tid >> 6, lane = tid & 63;
    int wr   = wv >> 1,  wc   = wv & 1;
    int quad = lane >> 4, l16 = lane & 15;
    int lr   = lane >> 3, lq = lane & 7;
    int sw   = (l16 & 7) * 8;                    // reader swizzle (elems)
    int lcs  = ((lq ^ lr) * 8);                  // DMA source chunk (elems)

    floatx4 acc[MS][4];
    floatx4 z4 = {0.f, 0.f, 0.f, 0.f};
#pragma unroll
    for (int mi = 0; mi < MS; mi++)
#pragma unroll
        for (int ni = 0; ni < 4; ni++) acc[mi][ni] = z4;

    auto STAGE = [&](int k0, int buf) {
        bf16_t* as = smem + buf * BUFSZ;
        bf16_t* bs = as + BM * 64;
#pragma unroll
        for (int i = 0; i < BM / 32; i++) {
            int r = wv * (BM / 4) + i * 8;
            gload16(&A[(size_t)(m0 + r + lr) * K + k0 + lcs], as + r * 64);
        }
#pragma unroll
        for (int i = 0; i < 4; i++) {
            int r = wv * 32 + i * 8;
            gload16(&Bt[(size_t)(n0 + r + lr) * K + k0 + lcs], bs + r * 64);
        }
    };

    STAGE(0, 0);
    int T = K >> 6;
    for (int t = 0; t < T; t++) {
        int cur = t & 1;
        __syncthreads();                 // buf[cur] DMA complete (1-tile cover)
        if (t + 1 < T) STAGE((t + 1) << 6, cur ^ 1);
        bf16_t (*As)[64] = (bf16_t(*)[64])(smem + cur * BUFSZ);
        bf16_t (*Bs)[64] = (bf16_t(*)[64])(smem + cur * BUFSZ + BM * 64);
#pragma unroll
        for (int kk = 0; kk < 2; kk++) {
            bf16x8 af[MS], bfr[4];
            int co = kk * 32 + quad * 8;
#pragma unroll
            for (int i = 0; i < MS; i++)
                af[i]  = *(const bf16x8*)&As[wr * (BM / 2) + i * 16 + l16][co ^ sw];
#pragma unroll
            for (int i = 0; i < 4; i++)
                bfr[i] = *(const bf16x8*)&Bs[wc * 64 + i * 16 + l16][co ^ sw];
#pragma unroll
            for (int mi = 0; mi < MS; mi++)
#pragma unroll
                for (int ni = 0; ni < 4; ni++)
                    acc[mi][ni] = __builtin_amdgcn_mfma_f32_16x16x32_bf16(
                        af[mi], bfr[ni], acc[mi][ni], 0, 0, 0);
        }
    }

    if constexpr (MODE == 1) {
        if (n0 >= 2048) {
            // ------- V tile: LDS transpose + permuted coalesced Vt write ----
            bf16_t (*Ts)[72] = (bf16_t(*)[72])smem;   // 128 hd x 64 s' (+pad)
            int bb = m0 >> 11, s0 = m0 & 2047;
            int hd0 = n0 & 1023;
#pragma unroll
            for (int mh = 0; mh < 2; mh++) {
                __syncthreads();
                if (wr == mh) {
#pragma unroll
                    for (int mi = 0; mi < MS; mi++)
#pragma unroll
                        for (int ni = 0; ni < 4; ni++)
#pragma unroll
                            for (int r = 0; r < 4; r++) {
                                int ml = mi * 16 + quad * 4 + r;     // 0..63
                                int nl = wc * 64 + ni * 16 + l16;    // 0..127
                                float v = acc[mi][ni][r] + bias2[hd0 + nl];
                                int sp = ((ml >> 5) << 5) | (((ml >> 2) & 3) << 3)
                                       | (((ml >> 4) & 1) << 2) | (ml & 3);
                                Ts[nl][sp] = (bf16_t)v;
                            }
                }
                __syncthreads();
#pragma unroll
                for (int i = 0; i < 4; i++) {
                    int c = tid + i * 256;          // 1024 chunk-writes
                    int row = c >> 3, ch = (c & 7) * 8;
                    int hh = row >> 6, dd = row & 63;
                    size_t off = (((size_t)bb * NHEAD + (hd0 >> 6) + hh) * HDIM + dd) * SEQ
                               + (size_t)(s0 + mh * 64 + ch);
                    *(bf16x8*)&vtout[off] = *(const bf16x8*)&Ts[row][ch];
                }
            }
            return;
        }
    }

    // epilogue: C/D layout col = lane&15 (n), row = quad*4 + reg (m)
#pragma unroll
    for (int mi = 0; mi < MS; mi++) {
#pragma unroll
        for (int ni = 0; ni < 4; ni++) {
            int n = n0 + wc * 64 + ni * 16 + l16;
#pragma unroll
            for (int r = 0; r < 4; r++) {
                int m = m0 + wr * (BM / 2) + mi * 16 + quad * 4 + r;
                float v = acc[mi][ni][r];
                if (MODE == 0) {
                    ((float*)outraw)[(size_t)m * N + n] = v + bias0[n];
                } else {
                    int which = n >> 10, cc = n & 1023;   // 0=Q, 1=K here
                    v += (which == 0) ? bias0[cc] : bias1[cc];
                    if (which == 0) v *= QSCALE;
                    int h = cc >> 6, d = cc & 63;
                    int b = m >> 11, s = m & 2047;
                    ((bf16_t*)outraw)[(size_t)which * 4194304u +
                        (((size_t)b * NHEAD + h) * SEQ + s) * HDIM + d] = (bf16_t)v;
                }
            }
        }
    }
}

// ---------------------------------------------------------------------------
// MFMA flash attention v4: S^T-trick + MS=4 (64 q-rows per wave).
// Each wave must read the FULL 16KB K+V tile from LDS regardless of q-rows,
// so LDS-per-MAC halves going 32->64 q/wave. 256 q-rows/block, grid 256
// (1 block/CU); exp2 total is tiling-invariant. DMA double-buffered K/V
// (32KB LDS), one barrier/tile with a full compute tile of prefetch cover.
// P never touches LDS (in-register repack into PV B-operand fragments);
// V stored key-permuted to match. Fixed-offset softmax exp2(s-16).
// ---------------------------------------------------------------------------
__global__ __launch_bounds__(256) void attn_mfma(
    const bf16_t* __restrict__ Q, const bf16_t* __restrict__ K,
    const bf16_t* __restrict__ Vt, bf16_t* __restrict__ O)
{
    __shared__ __align__(16) bf16_t Ks[2][64][64];   // [buf][key][dim]   swizzled
    __shared__ __align__(16) bf16_t Vs[2][64][64];   // [buf][dim][key']  swizzled

    int tid  = threadIdx.x;
    int wv   = tid >> 6, lane = tid & 63;
    int quad = lane >> 4, l16 = lane & 15;
    int lr   = lane >> 3, lq = lane & 7;
    int sw   = (l16 & 7) * 8;
    int flat = blockIdx.x;
    int hb   = flat & 31;               // head-batch group; XCD = flat%8 = hb%8
    int qt   = flat >> 5;               // q-tile 0..7 (256 rows each)
    int h = hb & 15, b = hb >> 4;
    int bh = b * NHEAD + h;
    int qw = qt * 256 + wv * 64;        // wave's first query row

    const bf16_t* Qb = Q  + (size_t)bh * SEQ * HDIM;
    const bf16_t* Kb = K  + (size_t)bh * SEQ * HDIM;
    const bf16_t* Vb = Vt + (size_t)bh * SEQ * HDIM;   // row d, col key'

    const bf16_t* kg = Kb + (size_t)(wv * 16 + lr) * HDIM + (lq ^ lr) * 8; // +t*4096
    const bf16_t* vg = Vb + (size_t)(wv * 16 + lr) * SEQ  + (lq ^ lr) * 8; // +t*64

    // Q fragments (B-operand: n=q=l16, k=dims), registers for whole kernel
    bf16x8 qf[4][2];
#pragma unroll
    for (int ms = 0; ms < 4; ms++)
#pragma unroll
        for (int kk = 0; kk < 2; kk++)
            qf[ms][kk] = *(const bf16x8*)
                &Qb[(size_t)(qw + ms * 16 + l16) * HDIM + kk * 32 + quad * 8];

    floatx4 o_acc[4][4];
    floatx4 z4  = {0.f, 0.f, 0.f, 0.f};
    floatx4 m16 = {-16.f, -16.f, -16.f, -16.f};
#pragma unroll
    for (int ms = 0; ms < 4; ms++)
#pragma unroll
        for (int nd = 0; nd < 4; nd++) o_acc[ms][nd] = z4;
    float l_i[4] = {0.f, 0.f, 0.f, 0.f};

    // prologue: stage tile 0 into buffer 0
    gload16(kg,           &Ks[0][wv * 16][0]);
    gload16(kg + 512,     &Ks[0][wv * 16 + 8][0]);
    gload16(vg,           &Vs[0][wv * 16][0]);
    gload16(vg + 8 * SEQ, &Vs[0][wv * 16 + 8][0]);

    for (int t = 0; t < 32; t++) {
        int cur = t & 1;
        __syncthreads();   // buf[cur] DMA done (prefetch had a full tile of cover)
        if (t < 31) {
            const bf16_t* kn = kg + (size_t)(t + 1) * 4096;
            const bf16_t* vn = vg + (size_t)(t + 1) * 64;
            int nb = cur ^ 1;
            gload16(kn,           &Ks[nb][wv * 16][0]);
            gload16(kn + 512,     &Ks[nb][wv * 16 + 8][0]);
            gload16(vn,           &Vs[nb][wv * 16][0]);
            gload16(vn + 8 * SEQ, &Vs[nb][wv * 16 + 8][0]);
        }

        // S^T - 16 = K @ Q^T - 16 : D[key][q], col=l16=q, row=quad*4+r=key
        floatx4 st[4][4];
#pragma unroll
        for (int ms = 0; ms < 4; ms++)
#pragma unroll
            for (int ns = 0; ns < 4; ns++) st[ms][ns] = m16;
#pragma unroll
        for (int ns = 0; ns < 4; ns++) {
#pragma unroll
            for (int kk = 0; kk < 2; kk++) {
                bf16x8 kf = *(const bf16x8*)
                    &Ks[cur][ns * 16 + l16][(kk * 32 + quad * 8) ^ sw];
#pragma unroll
                for (int ms = 0; ms < 4; ms++)
                    st[ms][ns] = __builtin_amdgcn_mfma_f32_16x16x32_bf16(
                        kf, qf[ms][kk], st[ms][ns], 0, 0, 0);
            }
        }

        // P^T = exp2(S^T); in-register repack into PV B-operand fragments:
        // pf[ms][kk][tt] = st[ms][2kk+(tt>>2)][tt&3]
        bf16x8 pf[4][2];
#pragma unroll
        for (int ms = 0; ms < 4; ms++) {
            float ls = 0.f;
#pragma unroll
            for (int kk = 0; kk < 2; kk++)
#pragma unroll
                for (int tt = 0; tt < 8; tt++) {
                    float p = __builtin_amdgcn_exp2f(st[ms][2 * kk + (tt >> 2)][tt & 3]);
                    ls += p;
                    pf[ms][kk][tt] = (bf16_t)p;
                }
            l_i[ms] += ls;
        }

        // O^T += V^T @ P : A = Vt frag (m=d), B = P^T frag (n=q)
#pragma unroll
        for (int nd = 0; nd < 4; nd++) {
#pragma unroll
            for (int kk = 0; kk < 2; kk++) {
                bf16x8 vf = *(const bf16x8*)
                    &Vs[cur][nd * 16 + l16][(kk * 32 + quad * 8) ^ sw];
#pragma unroll
                for (int ms = 0; ms < 4; ms++)
                    o_acc[ms][nd] = __builtin_amdgcn_mfma_f32_16x16x32_bf16(
                        vf, pf[ms][kk], o_acc[ms][nd], 0, 0, 0);
            }
        }
    }

    // l: lane holds partial for q = l16; sum across quads; store O^T
#pragma unroll
    for (int ms = 0; ms < 4; ms++) {
        float l = l_i[ms];
        l += __shfl_xor(l, 16);
        l += __shfl_xor(l, 32);
        float inv = 1.f / l;
        int q = qw + ms * 16 + l16;
        bf16_t* ob = O + ((size_t)b * SEQ + q) * EMBED + h * HDIM;
#pragma unroll
        for (int nd = 0; nd < 4; nd++)
#pragma unroll
            for (int r = 0; r < 4; r++)
                ob[nd * 16 + quad * 4 + r] = (bf16_t)(o_acc[ms][nd][r] * inv);
    }
}

// ---------------------------------------------------------------------------
// Workspace layout (bytes):
//   [0,  8MB): W^T bf16 (4 x 1M)
//   [8, 16MB): x bf16 [4096,1024]
//   [16,40MB): Q,K bf16 [b,h,s,d] (Q scaled by QSCALE); V slot unused
//   [40,48MB): Vt bf16 [b,h,d,s'] (key-permuted per 64-block, PV-operand map)
//   [48,56MB): attention out bf16 [b,s,h*d]
// ---------------------------------------------------------------------------
extern "C" void kernel_launch(void* const* d_in, const int* in_sizes, int n_in,
                              void* d_out, int out_size, void* d_ws, size_t ws_size,
                              hipStream_t stream)
{
    const float* x  = (const float*)d_in[0];
    const float* wq = (const float*)d_in[1];
    const float* bq = (const float*)d_in[2];
    const float* wk = (const float*)d_in[3];
    const float* bk = (const float*)d_in[4];
    const float* wv = (const float*)d_in[5];
    const float* bv = (const float*)d_in[6];
    const float* wo = (const float*)d_in[7];
    const float* bo = (const float*)d_in[8];

    char*   ws    = (char*)d_ws;
    bf16_t* Wt    = (bf16_t*)ws;                           // 4 x 1048576 bf16
    bf16_t* Xb    = (bf16_t*)(ws + 8ull  * 1024 * 1024);   // 4194304 bf16
    bf16_t* QKV   = (bf16_t*)(ws + 16ull * 1024 * 1024);   // 3 x 4194304 bf16
    bf16_t* Vt    = (bf16_t*)(ws + 40ull * 1024 * 1024);   // 4194304 bf16
    bf16_t* attnO = (bf16_t*)(ws + 48ull * 1024 * 1024);   // 4194304 bf16
    float*  outp  = (float*)d_out;

    // weights transpose + x convert, one launch
    transpose4<<<dim3(32, 32, 8), dim3(32, 8), 0, stream>>>(
        wq, wk, wv, wo, x, Wt, Xb);

    // fused QKV projection: Q/K -> [b,h,s,d]; V -> Vt [b,h,d,s'] directly
    gemm_t<128, 1><<<dim3(768), 256, 0, stream>>>(
        Xb, Wt, bq, bk, bv, QKV, Vt, MTOT, 3072, EMBED);

    attn_mfma<<<dim3(256), 256, 0, stream>>>(
        QKV, QKV + 4194304u, Vt, attnO);

    // output projection: [4096,1024] @ [1024,1024] -> d_out (fp32)
    gemm_t<64, 0><<<dim3(512), 256, 0, stream>>>(
        attnO, Wt + 3u * 1048576u, bo, bo, bo, outp, nullptr, MTOT, EMBED, EMBED);
}